// Round 1
// baseline (217.168 us; speedup 1.0000x reference)
//
#include <hip/hip_runtime.h>

#define BB   8
#define RR   128
#define SS   512
#define DD   33
#define EE   128
#define HH   4
#define EKK  32
#define NHH  128
#define HD   (HH*DD)      // 132
#define NEGV (-1000000000.0f)

// ---------------------------------------------------------------- sa (D=33)
__global__ void sa_kernel(const float* __restrict__ stride,
                          const float* __restrict__ Wr,
                          const float* __restrict__ br,
                          float* __restrict__ sa_ws,
                          float* __restrict__ out_tail) {
    int d = threadIdx.x;
    if (d < DD) {
        float acc = br[d];
        for (int j = 0; j < DD; ++j) acc += stride[j] * Wr[d * DD + j];
        float s = 1.0f / (1.0f + __expf(-acc));
        sa_ws[d]    = s;
        out_tail[d] = s;
    }
}

// ------------------------------------------------- q projection: qp[b,r,e]
__global__ __launch_bounds__(EE) void qproj_kernel(
        const float* __restrict__ query, const float* __restrict__ Wq,
        const float* __restrict__ bq, float* __restrict__ qp) {
    __shared__ float row[EE];
    int brid = blockIdx.x;          // b*R + r
    int e    = threadIdx.x;         // 0..127
    row[e] = query[brid * EE + e];
    __syncthreads();
    const float4* W4 = (const float4*)(Wq + e * EE);
    const float4* r4 = (const float4*)row;
    float acc = bq[e];
#pragma unroll
    for (int j = 0; j < EE / 4; ++j) {
        float4 w = W4[j]; float4 q = r4[j];
        acc += w.x * q.x + w.y * q.y + w.z * q.z + w.w * q.w;
    }
    qp[brid * EE + e] = acc;
}

// ----------------------------- k projection, transposed output: kt[b,e,s]
__global__ __launch_bounds__(EE) void kproj_kernel(
        const float* __restrict__ key, const float* __restrict__ Wk,
        const float* __restrict__ bk, float* __restrict__ kt) {
    __shared__ float row[EE];
    int bs = blockIdx.x;            // b*S + s
    int b = bs / SS, s = bs % SS;
    int e = threadIdx.x;
    row[e] = key[bs * EE + e];
    __syncthreads();
    const float4* W4 = (const float4*)(Wk + e * EE);
    const float4* r4 = (const float4*)row;
    float acc = bk[e];
#pragma unroll
    for (int j = 0; j < EE / 4; ++j) {
        float4 w = W4[j]; float4 q = r4[j];
        acc += w.x * q.x + w.y * q.y + w.z * q.z + w.w * q.w;
    }
    kt[(b * EE + e) * SS + s] = acc;
}

// -------------------------- transpose value & mask to [b][d][s] for coalesce
__global__ void transpose_vm(const float* __restrict__ value,
                             const float* __restrict__ mask,
                             float* __restrict__ vt,
                             float* __restrict__ mt) {
    int gid = blockIdx.x * blockDim.x + threadIdx.x;
    if (gid >= BB * DD * SS) return;
    int s   = gid % SS;
    int rem = gid / SS;
    int d   = rem % DD;
    int b   = rem / DD;
    float v = value[(b * SS + s) * DD + d];
    float m = mask [(b * SS + s) * DD + d];
    vt[gid] = v;
    mt[gid] = m;
}

// ------------------------------------------------------------- main fused
__global__ __launch_bounds__(256) void attn_kernel(
        const float* __restrict__ qp, const float* __restrict__ kt,
        const float* __restrict__ vt, const float* __restrict__ mt,
        const float* __restrict__ tt, const float* __restrict__ qt,
        const float* __restrict__ sa, const float* __restrict__ Wo,
        const float* __restrict__ bo, float* __restrict__ out) {
    __shared__ float s_sc[HH][SS];   // 8 KiB
    __shared__ float s_q[EE];
    __shared__ float s_tt[SS];
    __shared__ float s_sa[DD];
    __shared__ float s_x[HD];

    int brid = blockIdx.x;           // b*R + r
    int b = brid / RR, r = brid % RR;
    int tid  = threadIdx.x;
    int lane = tid & 63, wave = tid >> 6;

    if (tid < EE) s_q[tid] = qp[brid * EE + tid];
    s_tt[tid]       = tt[b * SS + tid];
    s_tt[tid + 256] = tt[b * SS + tid + 256];
    if (tid < DD) s_sa[tid] = sa[tid];
    __syncthreads();

    // ---- phase 1: scores[h][s] = (q_h . k_h,s) / sqrt(EK)
    const float scale = 0.17677669529663687f;   // 1/sqrt(32)
    for (int s = tid; s < SS; s += 256) {
#pragma unroll
        for (int h = 0; h < HH; ++h) {
            float acc = 0.f;
#pragma unroll
            for (int e = 0; e < EKK; ++e)
                acc += s_q[h * EKK + e] * kt[(b * EE + h * EKK + e) * SS + s];
            s_sc[h][s] = acc * scale;
        }
    }
    __syncthreads();

    // ---- phase 2: per-d masked softmax over s, all 4 heads per wave pass
    float qtr = qt[r];
    for (int d = wave; d < DD; d += 4) {
        float sad = s_sa[d];
        float lo = qtr - sad, hi = qtr + sad;

        float   vv[8];
        float   scv[8][HH];
        unsigned mbits = 0;
#pragma unroll
        for (int i = 0; i < 8; ++i) {
            int s = i * 64 + lane;
            float t = s_tt[s];
            float mv = mt[(b * DD + d) * SS + s];
            bool  m  = (t >= lo) && (t <= hi) && (mv != 0.f);
            if (m) mbits |= (1u << i);
            vv[i] = vt[(b * DD + d) * SS + s];
#pragma unroll
            for (int h = 0; h < HH; ++h) scv[i][h] = s_sc[h][s];
        }

        float mx[HH];
#pragma unroll
        for (int h = 0; h < HH; ++h) mx[h] = NEGV;
#pragma unroll
        for (int i = 0; i < 8; ++i) {
            bool m = (mbits >> i) & 1u;
#pragma unroll
            for (int h = 0; h < HH; ++h)
                mx[h] = fmaxf(mx[h], m ? scv[i][h] : NEGV);
        }
        for (int off = 32; off; off >>= 1) {
#pragma unroll
            for (int h = 0; h < HH; ++h)
                mx[h] = fmaxf(mx[h], __shfl_xor(mx[h], off));
        }

        float sum[HH], wsum[HH];
#pragma unroll
        for (int h = 0; h < HH; ++h) { sum[h] = 0.f; wsum[h] = 0.f; }
#pragma unroll
        for (int i = 0; i < 8; ++i) {
            bool m = (mbits >> i) & 1u;
#pragma unroll
            for (int h = 0; h < HH; ++h) {
                float val = m ? scv[i][h] : NEGV;
                float p   = __expf(val - mx[h]);
                sum[h]  += p;
                wsum[h] += p * vv[i];
            }
        }
        for (int off = 32; off; off >>= 1) {
#pragma unroll
            for (int h = 0; h < HH; ++h) {
                sum[h]  += __shfl_xor(sum[h],  off);
                wsum[h] += __shfl_xor(wsum[h], off);
            }
        }
        if (lane == 0) {
#pragma unroll
            for (int h = 0; h < HH; ++h)
                s_x[h * DD + d] = wsum[h] / sum[h];
        }
    }
    __syncthreads();

    // ---- phase 3: out[b,r,n] = x . Wo[n,:] + bo[n]
    if (tid < NHH) {
        float acc = bo[tid];
        const float* wrow = Wo + tid * HD;
#pragma unroll
        for (int j = 0; j < HD; ++j) acc += s_x[j] * wrow[j];
        out[brid * NHH + tid] = acc;
    }
}

// ------------------------------------------------------------------ launch
extern "C" void kernel_launch(void* const* d_in, const int* in_sizes, int n_in,
                              void* d_out, int out_size, void* d_ws, size_t ws_size,
                              hipStream_t stream) {
    const float* query  = (const float*)d_in[0];
    const float* key    = (const float*)d_in[1];
    const float* value  = (const float*)d_in[2];
    const float* mask   = (const float*)d_in[3];
    const float* qt     = (const float*)d_in[4];
    const float* tt     = (const float*)d_in[5];
    const float* stridev= (const float*)d_in[6];
    const float* Wq     = (const float*)d_in[7];
    const float* bq     = (const float*)d_in[8];
    const float* Wk     = (const float*)d_in[9];
    const float* bk     = (const float*)d_in[10];
    const float* Wr     = (const float*)d_in[11];
    const float* br     = (const float*)d_in[12];
    const float* Wo     = (const float*)d_in[13];
    const float* bo     = (const float*)d_in[14];

    float* out = (float*)d_out;                  // 131072 out + 33 sa
    float* ws  = (float*)d_ws;

    // workspace layout (floats)
    float* sa_ws = ws;                           // 64 (33 used)
    float* qp    = ws + 64;                      // B*R*E   = 131072
    float* kt    = qp + BB * RR * EE;            // B*E*S   = 524288
    float* vt    = kt + BB * EE * SS;            // B*D*S   = 135168
    float* mt    = vt + BB * DD * SS;            // B*D*S   = 135168

    sa_kernel<<<1, 64, 0, stream>>>(stridev, Wr, br, sa_ws, out + BB * RR * NHH);
    qproj_kernel<<<BB * RR, EE, 0, stream>>>(query, Wq, bq, qp);
    kproj_kernel<<<BB * SS, EE, 0, stream>>>(key, Wk, bk, kt);
    transpose_vm<<<(BB * DD * SS + 255) / 256, 256, 0, stream>>>(value, mask, vt, mt);
    attn_kernel<<<BB * RR, 256, 0, stream>>>(qp, kt, vt, mt, tt, qt, sa_ws,
                                             Wo, bo, out);
}

// Round 2
// 54.983 us; speedup vs baseline: 3.9497x; 3.9497x over previous
//
#include <hip/hip_runtime.h>

#define BB   8
#define RR   128
#define SS   512
#define DD   33
#define EE   128
#define HH   4
#define EKK  32
#define NHH  128
#define HD   (HH*DD)      // 132

// ---- workspace layout (float offsets) ----
#define WS_SA   0
#define WS_QP   64                               // B*H*R*EK = 131072
#define WS_KP   (WS_QP  + BB*RR*EE)              // B*S*E    = 524288
#define WS_VT   (WS_KP  + BB*SS*EE)              // B*D*S    = 135168
#define WS_MT   (WS_VT  + BB*DD*SS)              // B*D*S    = 135168
#define WS_WOT  (WS_MT  + BB*DD*SS)              // HD*NH    = 16896
#define WS_E    (WS_WOT + HD*NHH)                // B*H*R*S  = 2097152
#define WS_X    (WS_E   + BB*HH*RR*SS)           // B*R*HD   = 135168
// total = 3,174,976 floats = ~12.7 MB

#define NB_SA   1
#define NB_QP   (BB*RR/8)                        // 128
#define NB_KP   (BB*SS/8)                        // 512
#define NB_VM   ((BB*DD*SS + 127)/128)           // 1056
#define NB_WOT  ((HD*NHH + 127)/128)             // 132
#define NB_PREP (NB_SA + NB_QP + NB_KP + NB_VM + NB_WOT)   // 1829

// ============================================================== prep
__global__ __launch_bounds__(128) void prep_kernel(
    const float* __restrict__ query, const float* __restrict__ key,
    const float* __restrict__ value, const float* __restrict__ mask,
    const float* __restrict__ stridev,
    const float* __restrict__ Wq, const float* __restrict__ bq,
    const float* __restrict__ Wk, const float* __restrict__ bk,
    const float* __restrict__ Wr, const float* __restrict__ brv,
    const float* __restrict__ Wo,
    float* __restrict__ ws, float* __restrict__ out_tail)
{
    __shared__ float rows[8 * EE];     // 4 KB, used by proj branches
    int blk = blockIdx.x, tid = threadIdx.x;

    if (blk == 0) {                    // ---- sa (D=33)
        if (tid < DD) {
            float acc = brv[tid];
#pragma unroll
            for (int j = 0; j < DD; ++j) acc += stridev[j] * Wr[tid * DD + j];
            float sv = 1.0f / (1.0f + __expf(-acc));
            ws[WS_SA + tid] = sv;
            out_tail[tid]   = sv;
        }
        return;
    }
    blk -= NB_SA;

    if (blk < NB_QP) {                 // ---- q proj, 8 rows/block -> qp[b,h,r,ek]
        int br0 = blk * 8;
#pragma unroll
        for (int p = 0; p < 8; ++p) rows[p * EE + tid] = query[(br0 + p) * EE + tid];
        __syncthreads();
        float acc[8];
        float bv = bq[tid];
#pragma unroll
        for (int p = 0; p < 8; ++p) acc[p] = bv;
        const float4* W4 = (const float4*)(Wq + tid * EE);
        const float4* R4 = (const float4*)rows;
#pragma unroll
        for (int j = 0; j < EE / 4; ++j) {
            float4 w = W4[j];
#pragma unroll
            for (int p = 0; p < 8; ++p) {
                float4 rv = R4[p * 32 + j];
                acc[p] += w.x * rv.x + w.y * rv.y + w.z * rv.z + w.w * rv.w;
            }
        }
        int h = tid >> 5, ek = tid & 31;
        int b = br0 / RR;
#pragma unroll
        for (int p = 0; p < 8; ++p) {
            int r = (br0 + p) - b * RR;
            ws[WS_QP + ((b * HH + h) * RR + r) * EKK + ek] = acc[p];
        }
        return;
    }
    blk -= NB_QP;

    if (blk < NB_KP) {                 // ---- k proj, 8 rows/block -> kp[b,s,e]
        int s8 = blk * 8;              // row index into (b*S + s)
#pragma unroll
        for (int p = 0; p < 8; ++p) rows[p * EE + tid] = key[(s8 + p) * EE + tid];
        __syncthreads();
        float acc[8];
        float bv = bk[tid];
#pragma unroll
        for (int p = 0; p < 8; ++p) acc[p] = bv;
        const float4* W4 = (const float4*)(Wk + tid * EE);
        const float4* R4 = (const float4*)rows;
#pragma unroll
        for (int j = 0; j < EE / 4; ++j) {
            float4 w = W4[j];
#pragma unroll
            for (int p = 0; p < 8; ++p) {
                float4 rv = R4[p * 32 + j];
                acc[p] += w.x * rv.x + w.y * rv.y + w.z * rv.z + w.w * rv.w;
            }
        }
#pragma unroll
        for (int p = 0; p < 8; ++p)
            ws[WS_KP + (s8 + p) * EE + tid] = acc[p];
        return;
    }
    blk -= NB_KP;

    if (blk < NB_VM) {                 // ---- value/mask transpose -> [b,d,s]
        int gid = blk * 128 + tid;
        if (gid < BB * DD * SS) {
            int s = gid % SS, rem = gid / SS;
            int d = rem % DD, b = rem / DD;
            ws[WS_VT + gid] = value[(b * SS + s) * DD + d];
            ws[WS_MT + gid] = mask [(b * SS + s) * DD + d];
        }
        return;
    }
    blk -= NB_VM;

    {                                  // ---- Wo transpose -> wot[j][n]
        int gid = blk * 128 + tid;
        if (gid < HD * NHH) {
            int n = gid & 127, j = gid >> 7;
            ws[WS_WOT + gid] = Wo[n * HD + j];
        }
    }
}

// ===================================================== scores -> exp(score)
// grid: blk = bh*16 + rt*2 + st ; bh in [0,32), rt in [0,8), st in [0,2)
__global__ __launch_bounds__(256) void scores_kernel(
    const float* __restrict__ qp, const float* __restrict__ kp,
    float* __restrict__ E)
{
    __shared__ float s_q[16 * EKK];        // 2 KB
    __shared__ float s_k[256 * 33];        // 33.8 KB (pad 32->33 kills conflicts)
    int blk = blockIdx.x, tid = threadIdx.x;
    int st = blk & 1;
    int rt = (blk >> 1) & 7;
    int bh = blk >> 4;
    int s0 = st * 256, r0 = rt * 16;

    // stage q tile (16 r x 32 ek = 512 floats)
    const float* qsrc = qp + (bh * RR + r0) * EKK;
    s_q[tid]       = qsrc[tid];
    s_q[tid + 256] = qsrc[tid + 256];

    // stage k tile (256 s x 32 ek)
    int b = bh >> 2, h = bh & 3;
    const float* ksrc = kp + (b * SS + s0) * EE + h * EKK;
#pragma unroll
    for (int p = 0; p < 32; ++p) {
        int idx  = p * 256 + tid;
        int srow = idx >> 5, ek = idx & 31;
        s_k[srow * 33 + ek] = ksrc[srow * EE + ek];
    }
    __syncthreads();

    float kr[32];
#pragma unroll
    for (int e = 0; e < 32; ++e) kr[e] = s_k[tid * 33 + e];

    const float scale = 0.17677669529663687f;   // 1/sqrt(32)
    float* Eout = E + (bh * RR + r0) * SS + s0 + tid;
    const float4* q4 = (const float4*)s_q;
#pragma unroll
    for (int rr = 0; rr < 16; rr += 2) {
        float a0 = 0.f, a1 = 0.f;
#pragma unroll
        for (int eq = 0; eq < 8; ++eq) {
            float4 qa = q4[rr * 8 + eq];
            float4 qb = q4[rr * 8 + 8 + eq];
            a0 += qa.x * kr[eq*4] + qa.y * kr[eq*4+1] + qa.z * kr[eq*4+2] + qa.w * kr[eq*4+3];
            a1 += qb.x * kr[eq*4] + qb.y * kr[eq*4+1] + qb.z * kr[eq*4+2] + qb.w * kr[eq*4+3];
        }
        Eout[rr * SS]       = __expf(a0 * scale);
        Eout[(rr + 1) * SS] = __expf(a1 * scale);
    }
}

// ============================================ softmax + PV : one wave = (b,r,d)
// grid: blk = br*9 + dc ... actually blk/9 = br, blk%9 = dc ; wave w -> d = dc*4+w
__global__ __launch_bounds__(256) void softmax_kernel(
    const float* __restrict__ E, const float* __restrict__ vt,
    const float* __restrict__ mt, const float* __restrict__ tt,
    const float* __restrict__ qt, const float* __restrict__ sa,
    float* __restrict__ x)
{
    __shared__ float s_e[HH * SS];     // 8 KB  (exp-scores, 4 heads)
    __shared__ float s_tt[SS];         // 2 KB
    int blk = blockIdx.x, tid = threadIdx.x;
    int dc = blk % 9;
    int br = blk / 9;
    int b  = br >> 7, r = br & 127;

    float4* se4 = (float4*)s_e;
#pragma unroll
    for (int p = 0; p < 2; ++p) {
        int f = p * 256 + tid;                 // 0..511 float4s
        int h = f >> 7, off = f & 127;
        se4[f] = ((const float4*)(E + ((b * HH + h) * RR + r) * SS))[off];
    }
    if (tid < 128) ((float4*)s_tt)[tid] = ((const float4*)(tt + b * SS))[tid];
    __syncthreads();

    int wave = tid >> 6, lane = tid & 63;
    int d = dc * 4 + wave;
    if (d >= DD) return;

    float qtr = qt[r];
    float sad = sa[d];
    float lo = qtr - sad, hi = qtr + sad;

    int sb = lane * 8;
    const float4* mv4 = (const float4*)(mt + (b * DD + d) * SS + sb);
    const float4* vv4 = (const float4*)(vt + (b * DD + d) * SS + sb);
    float4 m0 = mv4[0], m1 = mv4[1];
    float4 v0 = vv4[0], v1 = vv4[1];
    const float4* t4 = (const float4*)(s_tt + sb);
    float4 t0 = t4[0], t1 = t4[1];

    float tv[8] = {t0.x,t0.y,t0.z,t0.w,t1.x,t1.y,t1.z,t1.w};
    float mv[8] = {m0.x,m0.y,m0.z,m0.w,m1.x,m1.y,m1.z,m1.w};
    float vv[8] = {v0.x,v0.y,v0.z,v0.w,v1.x,v1.y,v1.z,v1.w};
    bool  mk[8];
#pragma unroll
    for (int i = 0; i < 8; ++i)
        mk[i] = (tv[i] >= lo) & (tv[i] <= hi) & (mv[i] != 0.f);

    float psum[HH] = {0,0,0,0}, wsum[HH] = {0,0,0,0};
#pragma unroll
    for (int h = 0; h < HH; ++h) {
        const float4* e4 = (const float4*)(s_e + h * SS + sb);
        float4 e0 = e4[0], e1 = e4[1];
        float ev[8] = {e0.x,e0.y,e0.z,e0.w,e1.x,e1.y,e1.z,e1.w};
#pragma unroll
        for (int i = 0; i < 8; ++i) {
            float p = mk[i] ? ev[i] : 0.f;
            psum[h] += p;
            wsum[h] += p * vv[i];
        }
    }
#pragma unroll
    for (int off = 32; off; off >>= 1) {
#pragma unroll
        for (int h = 0; h < HH; ++h) {
            psum[h] += __shfl_xor(psum[h], off);
            wsum[h] += __shfl_xor(wsum[h], off);
        }
    }

    // all-masked fallback: softmax of all-NEG is uniform -> mean(value)
    bool anyz = (psum[0]==0.f) | (psum[1]==0.f) | (psum[2]==0.f) | (psum[3]==0.f);
    float vall = 0.f;
    if (anyz) {
#pragma unroll
        for (int i = 0; i < 8; ++i) vall += vv[i];
#pragma unroll
        for (int off = 32; off; off >>= 1) vall += __shfl_xor(vall, off);
    }

    if (lane == 0) {
        float* xd = x + br * HD + d;
#pragma unroll
        for (int h = 0; h < HH; ++h)
            xd[h * DD] = (psum[h] > 0.f) ? (wsum[h] / psum[h])
                                         : (vall * (1.0f / SS));
    }
}

// ================================================================= out GEMV
__global__ __launch_bounds__(128) void gemv_kernel(
    const float* __restrict__ x, const float* __restrict__ wot,
    const float* __restrict__ bo, float* __restrict__ out)
{
    __shared__ float s_x[HD];
    int br = blockIdx.x, tid = threadIdx.x;
    const float* xr = x + br * HD;
    s_x[tid] = xr[tid];
    if (tid < HD - 128) s_x[128 + tid] = xr[128 + tid];
    __syncthreads();
    float acc = bo[tid];
#pragma unroll
    for (int j = 0; j < HD; ++j) acc += s_x[j] * wot[j * NHH + tid];
    out[br * NHH + tid] = acc;
}

// ================================================================== launch
extern "C" void kernel_launch(void* const* d_in, const int* in_sizes, int n_in,
                              void* d_out, int out_size, void* d_ws, size_t ws_size,
                              hipStream_t stream) {
    const float* query   = (const float*)d_in[0];
    const float* key     = (const float*)d_in[1];
    const float* value   = (const float*)d_in[2];
    const float* mask    = (const float*)d_in[3];
    const float* qt      = (const float*)d_in[4];
    const float* tt      = (const float*)d_in[5];
    const float* stridev = (const float*)d_in[6];
    const float* Wq      = (const float*)d_in[7];
    const float* bq      = (const float*)d_in[8];
    const float* Wk      = (const float*)d_in[9];
    const float* bk      = (const float*)d_in[10];
    const float* Wr      = (const float*)d_in[11];
    const float* brv     = (const float*)d_in[12];
    const float* Wo      = (const float*)d_in[13];
    const float* bo      = (const float*)d_in[14];

    float* out = (float*)d_out;               // 131072 out + 33 sa
    float* ws  = (float*)d_ws;

    prep_kernel<<<NB_PREP, 128, 0, stream>>>(
        query, key, value, mask, stridev, Wq, bq, Wk, bk, Wr, brv, Wo,
        ws, out + BB * RR * NHH);
    scores_kernel<<<512, 256, 0, stream>>>(ws + WS_QP, ws + WS_KP, ws + WS_E);
    softmax_kernel<<<BB * RR * 9, 256, 0, stream>>>(
        ws + WS_E, ws + WS_VT, ws + WS_MT, tt, qt, ws + WS_SA, ws + WS_X);
    gemv_kernel<<<BB * RR, 128, 0, stream>>>(ws + WS_X, ws + WS_WOT, bo, out);
}

// Round 3
// 50.721 us; speedup vs baseline: 4.2816x; 1.0840x over previous
//
#include <hip/hip_runtime.h>

#define BB   8
#define RR   128
#define SS   512
#define DD   33
#define EE   128
#define HH   4
#define EKK  32
#define NHH  128
#define HD   (HH*DD)      // 132

// ---- workspace layout (float offsets) ----
#define WS_SA   0
#define WS_QP   64                               // B*R*E  = 131072 (row-major)
#define WS_KT   (WS_QP  + BB*RR*EE)              // B*E*S  = 524288 (transposed)
#define WS_VT   (WS_KT  + BB*EE*SS)              // B*D*S  = 135168
#define WS_MT   (WS_VT  + BB*DD*SS)              // B*D*S  = 135168
#define WS_WOT  (WS_MT  + BB*DD*SS)              // HD*NH  = 16896
// total ~3.8 MB

#define NB_SA   1
#define NB_QP   (BB*RR/8)                        // 128
#define NB_KT   (BB*SS/16)                       // 256
#define NB_VM   ((BB*DD*SS + 127)/128)           // 1056
#define NB_WOT  ((HD*NHH + 127)/128)             // 132
#define NB_PREP (NB_SA + NB_QP + NB_KT + NB_VM + NB_WOT)

// ============================================================== K1: prep
__global__ __launch_bounds__(128) void prep_kernel(
    const float* __restrict__ query, const float* __restrict__ key,
    const float* __restrict__ value, const float* __restrict__ mask,
    const float* __restrict__ stridev,
    const float* __restrict__ Wq, const float* __restrict__ bq,
    const float* __restrict__ Wk, const float* __restrict__ bk,
    const float* __restrict__ Wr, const float* __restrict__ brv,
    const float* __restrict__ Wo,
    float* __restrict__ ws, float* __restrict__ out_tail)
{
    __shared__ float rows[16 * EE];    // 8 KB
    int blk = blockIdx.x, tid = threadIdx.x;

    if (blk == 0) {                    // ---- sa (D=33)
        if (tid < DD) {
            float acc = brv[tid];
#pragma unroll
            for (int j = 0; j < DD; ++j) acc += stridev[j] * Wr[tid * DD + j];
            float sv = 1.0f / (1.0f + __expf(-acc));
            ws[WS_SA + tid] = sv;
            out_tail[tid]   = sv;
        }
        return;
    }
    blk -= NB_SA;

    if (blk < NB_QP) {                 // ---- q proj, 8 rows -> qp[b,r,e]
        int br0 = blk * 8;
#pragma unroll
        for (int p = 0; p < 8; ++p) rows[p * EE + tid] = query[(br0 + p) * EE + tid];
        __syncthreads();
        float acc[8];
        float bv = bq[tid];
#pragma unroll
        for (int p = 0; p < 8; ++p) acc[p] = bv;
        const float4* W4 = (const float4*)(Wq + tid * EE);
        const float4* R4 = (const float4*)rows;
#pragma unroll
        for (int j = 0; j < EE / 4; ++j) {
            float4 w = W4[j];
#pragma unroll
            for (int p = 0; p < 8; ++p) {
                float4 rv = R4[p * 32 + j];
                acc[p] += w.x * rv.x + w.y * rv.y + w.z * rv.z + w.w * rv.w;
            }
        }
#pragma unroll
        for (int p = 0; p < 8; ++p)
            ws[WS_QP + (br0 + p) * EE + tid] = acc[p];
        return;
    }
    blk -= NB_QP;

    if (blk < NB_KT) {                 // ---- k proj, 16 rows -> kt[b,e,s]
        int s16 = blk * 16;            // global row index b*S + s0
#pragma unroll
        for (int p = 0; p < 16; ++p) rows[p * EE + tid] = key[(s16 + p) * EE + tid];
        __syncthreads();
        float acc[16];
        float bv = bk[tid];
#pragma unroll
        for (int p = 0; p < 16; ++p) acc[p] = bv;
        const float4* W4 = (const float4*)(Wk + tid * EE);
        const float4* R4 = (const float4*)rows;
#pragma unroll
        for (int j = 0; j < EE / 4; ++j) {
            float4 w = W4[j];
#pragma unroll
            for (int p = 0; p < 16; ++p) {
                float4 rv = R4[p * 32 + j];
                acc[p] += w.x * rv.x + w.y * rv.y + w.z * rv.z + w.w * rv.w;
            }
        }
        int b = s16 / SS, s0 = s16 % SS;
        // each thread owns row e=tid: 16 consecutive s = one 64B line
        float4* dst = (float4*)(ws + WS_KT + (b * EE + tid) * SS + s0);
#pragma unroll
        for (int q4 = 0; q4 < 4; ++q4) {
            float4 v; v.x = acc[q4*4]; v.y = acc[q4*4+1]; v.z = acc[q4*4+2]; v.w = acc[q4*4+3];
            dst[q4] = v;
        }
        return;
    }
    blk -= NB_KT;

    if (blk < NB_VM) {                 // ---- value/mask transpose -> [b,d,s]
        int gid = blk * 128 + tid;
        if (gid < BB * DD * SS) {
            int s = gid % SS, rem = gid / SS;
            int d = rem % DD, b = rem / DD;
            ws[WS_VT + gid] = value[(b * SS + s) * DD + d];
            ws[WS_MT + gid] = mask [(b * SS + s) * DD + d];
        }
        return;
    }
    blk -= NB_VM;

    {                                  // ---- Wo transpose -> wot[j][n]
        int gid = blk * 128 + tid;
        if (gid < HD * NHH) {
            int n = gid & 127, j = gid >> 7;
            ws[WS_WOT + gid] = Wo[n * HD + j];
        }
    }
}

// ========================== K2: scores + masked softmax + PV + out-GEMV
// one block per (b,r), 512 threads (8 waves)
__global__ __launch_bounds__(512) void fused_kernel(
    const float* __restrict__ qp, const float* __restrict__ kt,
    const float* __restrict__ vt, const float* __restrict__ mt,
    const float* __restrict__ tt, const float* __restrict__ qt,
    const float* __restrict__ sa, const float* __restrict__ wot,
    const float* __restrict__ bo, float* __restrict__ out)
{
    __shared__ float s_q[EE];          // 512 B
    __shared__ float s_tt[SS];         // 2 KB
    __shared__ float s_sa[DD];
    __shared__ float s_e[HH * SS];     // 8 KB (exp of scores)
    __shared__ float s_x[HD];          // 528 B
    __shared__ float s_part[4][NHH];   // 2 KB

    int brid = blockIdx.x;
    int b = brid >> 7, r = brid & 127;
    int tid = threadIdx.x;

    if (tid < EE) s_q[tid] = qp[brid * EE + tid];
    s_tt[tid] = tt[b * SS + tid];
    if (tid < DD) s_sa[tid] = sa[tid];
    __syncthreads();

    // ---- phase A: E[h][s] = exp(score), straight into LDS
    {
        int h = tid >> 7, sg = tid & 127;      // 4 float-s per thread
        const float4* ktb = (const float4*)kt + (b * EE + h * EKK) * (SS/4) + sg;
        float4 acc = {0.f, 0.f, 0.f, 0.f};
#pragma unroll
        for (int e = 0; e < EKK; ++e) {
            float4 kv = ktb[e * (SS/4)];
            float  qv = s_q[h * EKK + e];
            acc.x += qv * kv.x; acc.y += qv * kv.y;
            acc.z += qv * kv.z; acc.w += qv * kv.w;
        }
        const float scale = 0.17677669529663687f;    // 1/sqrt(32)
        float4 ev;
        ev.x = __expf(acc.x * scale); ev.y = __expf(acc.y * scale);
        ev.z = __expf(acc.z * scale); ev.w = __expf(acc.w * scale);
        ((float4*)s_e)[h * (SS/4) + sg] = ev;
    }
    __syncthreads();

    // ---- phase B: per-d masked softmax + PV (wave per d, 5 rounds)
    int wave = tid >> 6, lane = tid & 63;
    float qtr = qt[r];
#pragma unroll
    for (int rd = 0; rd < 5; ++rd) {
        int d = rd * 8 + wave;
        if (d < DD) {
            float sad = s_sa[d];
            float lo = qtr - sad, hi = qtr + sad;

            int sb = lane * 8;
            const float4* mv4 = (const float4*)(mt + (b * DD + d) * SS + sb);
            const float4* vv4 = (const float4*)(vt + (b * DD + d) * SS + sb);
            float4 m0 = mv4[0], m1 = mv4[1];
            float4 v0 = vv4[0], v1 = vv4[1];
            const float4* t4 = (const float4*)(s_tt + sb);
            float4 t0 = t4[0], t1 = t4[1];

            float tv[8] = {t0.x,t0.y,t0.z,t0.w,t1.x,t1.y,t1.z,t1.w};
            float mv[8] = {m0.x,m0.y,m0.z,m0.w,m1.x,m1.y,m1.z,m1.w};
            float vv[8] = {v0.x,v0.y,v0.z,v0.w,v1.x,v1.y,v1.z,v1.w};
            bool  mk[8];
#pragma unroll
            for (int i = 0; i < 8; ++i)
                mk[i] = (tv[i] >= lo) & (tv[i] <= hi) & (mv[i] != 0.f);

            float psum[HH] = {0,0,0,0}, wsum[HH] = {0,0,0,0};
#pragma unroll
            for (int h = 0; h < HH; ++h) {
                const float4* e4 = (const float4*)(s_e + h * SS + sb);
                float4 e0 = e4[0], e1 = e4[1];
                float ev[8] = {e0.x,e0.y,e0.z,e0.w,e1.x,e1.y,e1.z,e1.w};
#pragma unroll
                for (int i = 0; i < 8; ++i) {
                    float p = mk[i] ? ev[i] : 0.f;
                    psum[h] += p;
                    wsum[h] += p * vv[i];
                }
            }
#pragma unroll
            for (int off = 32; off; off >>= 1) {
#pragma unroll
                for (int h = 0; h < HH; ++h) {
                    psum[h] += __shfl_xor(psum[h], off);
                    wsum[h] += __shfl_xor(wsum[h], off);
                }
            }

            // all-masked fallback: softmax of all-NEG -> uniform -> mean(v)
            bool anyz = (psum[0]==0.f) | (psum[1]==0.f) |
                        (psum[2]==0.f) | (psum[3]==0.f);
            float vall = 0.f;
            if (anyz) {
#pragma unroll
                for (int i = 0; i < 8; ++i) vall += vv[i];
#pragma unroll
                for (int off = 32; off; off >>= 1) vall += __shfl_xor(vall, off);
            }

            if (lane == 0) {
#pragma unroll
                for (int h = 0; h < HH; ++h)
                    s_x[h * DD + d] = (psum[h] > 0.f) ? (wsum[h] / psum[h])
                                                      : (vall * (1.0f / SS));
            }
        }
    }
    __syncthreads();

    // ---- phase C: out[n] = x . Wo[n,:] + bo[n], 4-way j-split
    {
        int g = tid >> 7, n = tid & 127;       // 132 = 4*33
        float acc = 0.f;
#pragma unroll
        for (int j = 0; j < 33; ++j)
            acc += s_x[g * 33 + j] * wot[(g * 33 + j) * NHH + n];
        s_part[g][n] = acc;
    }
    __syncthreads();
    if (tid < NHH)
        out[brid * NHH + tid] = bo[tid] + s_part[0][tid] + s_part[1][tid]
                              + s_part[2][tid] + s_part[3][tid];
}

// ================================================================== launch
extern "C" void kernel_launch(void* const* d_in, const int* in_sizes, int n_in,
                              void* d_out, int out_size, void* d_ws, size_t ws_size,
                              hipStream_t stream) {
    const float* query   = (const float*)d_in[0];
    const float* key     = (const float*)d_in[1];
    const float* value   = (const float*)d_in[2];
    const float* mask    = (const float*)d_in[3];
    const float* qt      = (const float*)d_in[4];
    const float* tt      = (const float*)d_in[5];
    const float* stridev = (const float*)d_in[6];
    const float* Wq      = (const float*)d_in[7];
    const float* bq      = (const float*)d_in[8];
    const float* Wk      = (const float*)d_in[9];
    const float* bk      = (const float*)d_in[10];
    const float* Wr      = (const float*)d_in[11];
    const float* brv     = (const float*)d_in[12];
    const float* Wo      = (const float*)d_in[13];
    const float* bo      = (const float*)d_in[14];

    float* out = (float*)d_out;               // 131072 out + 33 sa
    float* ws  = (float*)d_ws;

    prep_kernel<<<NB_PREP, 128, 0, stream>>>(
        query, key, value, mask, stridev, Wq, bq, Wk, bk, Wr, brv, Wo,
        ws, out + BB * RR * NHH);
    fused_kernel<<<BB * RR, 512, 0, stream>>>(
        ws + WS_QP, ws + WS_KT, ws + WS_VT, ws + WS_MT,
        tt, qt, ws + WS_SA, ws + WS_WOT, bo, out);
}